// Round 15
// baseline (192.974 us; speedup 1.0000x reference)
//
#include <hip/hip_runtime.h>

#define N_NODES 50000
#define M_NODES 50000
#define N_EDGES 800000
#define NFEAT   300
#define NHID    256
#define NCLASS  20
#define N_IDX   5000
#define KTILES  10          // ceil(300/32) for gemm1
#define K2TILES 8           // 256/32 for gemm2
#define NTOT    (M_NODES + N_NODES)
#define MARKW   ((N_NODES + 31) / 32)
#define GEMM1_BLOCKS ((N_NODES + 63) / 64)     // 782
#define EB4_BLOCKS   ((N_EDGES + 1023) / 1024) // 782

typedef __attribute__((ext_vector_type(8))) short bf16x8;
typedef __attribute__((ext_vector_type(4))) float f32x4;

__device__ inline unsigned short f2bf(float f) {
    unsigned u = __float_as_uint(f);
    u += 0x7fff + ((u >> 16) & 1);          // round-to-nearest-even
    return (unsigned short)(u >> 16);
}
__device__ inline float bf2f(unsigned short h) { return __uint_as_float((unsigned)h << 16); }
__device__ inline float bflo(unsigned v) { return __uint_as_float(v << 16); }
__device__ inline float bfhi(unsigned v) { return __uint_as_float(v & 0xffff0000u); }

// ---------------------------------------------------------------------------
// Fused prep: blocks [0,320) W1 -> k-tiled hi/lo bf16;
//             blocks [320,340) mark bitmask;
//             blocks [340,372) W2 -> k-tiled hi/lo bf16 (cols padded to 32).
// ---------------------------------------------------------------------------
__global__ __launch_bounds__(256) void prep_kernel(const float* __restrict__ W1,
                                                   unsigned short* __restrict__ w1h,
                                                   unsigned short* __restrict__ w1l,
                                                   const int* __restrict__ idx,
                                                   unsigned* __restrict__ markbits,
                                                   const float* __restrict__ W2,
                                                   unsigned short* __restrict__ w2h,
                                                   unsigned short* __restrict__ w2l) {
    if (blockIdx.x < 320) {
        int id = blockIdx.x * 256 + threadIdx.x;        // 320*256 total
        int col = id & 255;
        int k   = id >> 8;                              // 0..319
        float v = (k < NFEAT) ? W1[(size_t)k * NHID + col] : 0.f;
        unsigned short hi = f2bf(v);
        unsigned short lo = f2bf(v - bf2f(hi));
        size_t off = (size_t)(k >> 5) * (256 * 32) + (size_t)col * 32 + (k & 31);
        w1h[off] = hi;
        w1l[off] = lo;
    } else if (blockIdx.x < 340) {
        int i = (blockIdx.x - 320) * 256 + threadIdx.x;
        if (i < N_IDX) {
            int r = idx[i];
            atomicOr(&markbits[r >> 5], 1u << (r & 31));
        }
    } else {
        int id = (blockIdx.x - 340) * 256 + threadIdx.x;  // 8192 = 256k x 32col
        int col = id & 31;
        int k   = id >> 5;                                // 0..255
        float v = (col < NCLASS) ? W2[(size_t)k * NCLASS + col] : 0.f;
        unsigned short hi = f2bf(v);
        unsigned short lo = f2bf(v - bf2f(hi));
        size_t off = (size_t)(k >> 5) * (32 * 32) + (size_t)col * 32 + (k & 31);
        w2h[off] = hi;
        w2l[off] = lo;
    }
}

// ---------------------------------------------------------------------------
// Combined histogram + rank capture (4 edges/thread for MLP)
// ---------------------------------------------------------------------------
__global__ __launch_bounds__(256) void hist_both_kernel(const int* __restrict__ fn_rows,
                                                        const int* __restrict__ nf_rows,
                                                        const unsigned* __restrict__ markbits,
                                                        int* __restrict__ counts,
                                                        unsigned short* __restrict__ fn_rank,
                                                        unsigned short* __restrict__ nf_rank) {
    const int base = blockIdx.x * 1024 + threadIdx.x;
    int r[4], r2[4], m2[4];
#pragma unroll
    for (int k = 0; k < 4; ++k) {
        int e = base + k * 256;
        r[k]  = (e < N_EDGES) ? fn_rows[e] : -1;
        r2[k] = (e < N_EDGES) ? nf_rows[e] : -1;
    }
#pragma unroll
    for (int k = 0; k < 4; ++k)
        m2[k] = (r2[k] >= 0) ? (int)((markbits[r2[k] >> 5] >> (r2[k] & 31)) & 1u) : 0;
#pragma unroll
    for (int k = 0; k < 4; ++k) {
        if (r[k] >= 0) {
            int p = atomicAdd(&counts[r[k]], 1);
            fn_rank[base + k * 256] = (unsigned short)p;
        }
    }
#pragma unroll
    for (int k = 0; k < 4; ++k) {
        if (m2[k]) {
            int p = atomicAdd(&counts[M_NODES + r2[k]], 1);
            nf_rank[base + k * 256] = (unsigned short)p;
        }
    }
}

// ---------------------------------------------------------------------------
// Scan pass 1: per-chunk inclusive scan + chunk totals
// ---------------------------------------------------------------------------
__global__ __launch_bounds__(256) void scan_chunk_kernel(const int* __restrict__ counts,
                                                         int* __restrict__ chunk_incl,
                                                         int* __restrict__ chunk_sums, int n) {
    __shared__ int lds[256];
    int i = blockIdx.x * 256 + threadIdx.x;
    int v = (i < n) ? counts[i] : 0;
    lds[threadIdx.x] = v;
    __syncthreads();
    for (int off = 1; off < 256; off <<= 1) {
        int t = (threadIdx.x >= off) ? lds[threadIdx.x - off] : 0;
        __syncthreads();
        lds[threadIdx.x] += t;
        __syncthreads();
    }
    if (i < n) chunk_incl[i] = lds[threadIdx.x];
    if (threadIdx.x == 255) chunk_sums[blockIdx.x] = lds[255];
}

// ---------------------------------------------------------------------------
// Scan pass 2 (merged): per-block prefix over chunk_sums + apply.
// ---------------------------------------------------------------------------
__global__ __launch_bounds__(256) void scan_finish_kernel(const int* __restrict__ counts,
                                                          const int* __restrict__ chunk_incl,
                                                          const int* __restrict__ chunk_sums,
                                                          int* __restrict__ row_ptr,
                                                          int n, int nchunks) {
    __shared__ int lds[256];
    const int b = blockIdx.x;
    int partial = 0;
    for (int i = threadIdx.x; i < b; i += 256) partial += chunk_sums[i];
    lds[threadIdx.x] = partial;
    __syncthreads();
    for (int off = 128; off > 0; off >>= 1) {
        if (threadIdx.x < off) lds[threadIdx.x] += lds[threadIdx.x + off];
        __syncthreads();
    }
    const int coff = lds[0];
    int i = b * 256 + threadIdx.x;
    if (i < n) row_ptr[i] = chunk_incl[i] - counts[i] + coff;
    if (b == nchunks - 1 && threadIdx.x == 0) row_ptr[n] = coff + chunk_sums[b];
}

// ---------------------------------------------------------------------------
// FUSED gemm1 + scatter, CONTIGUOUS ranges. K-loop reordered so next-tile
// global loads are issued AFTER the barrier (the compiler's s_waitcnt
// vmcnt(0)-before-s_barrier no longer drains the prefetch; loads land under
// the 48-MFMA compute phase).
// ---------------------------------------------------------------------------
__global__ __launch_bounds__(256) void gemm1_scatter_kernel(
        const float* __restrict__ x,
        const unsigned short* __restrict__ w1h,
        const unsigned short* __restrict__ w1l,
        unsigned short* __restrict__ xwb,
        const int* __restrict__ fn_rows, const int* __restrict__ fn_cols,
        const float* __restrict__ fn_vals,
        const int* __restrict__ nf_rows, const int* __restrict__ nf_cols,
        const float* __restrict__ nf_vals,
        const unsigned* __restrict__ markbits,
        const int* __restrict__ row_ptr,
        const unsigned short* __restrict__ fn_rank,
        const unsigned short* __restrict__ nf_rank,
        uint2* __restrict__ csr_cv) {
    __shared__ unsigned short Ah[2][64 * 40];   // 40 = 32 + 8 pad (80B rows)
    __shared__ unsigned short Al[2][64 * 40];

    if (blockIdx.x >= GEMM1_BLOCKS) {
        // ---------------- scatter half ----------------
        const int base = (blockIdx.x - GEMM1_BLOCKS) * 1024 + threadIdx.x;
#pragma unroll
        for (int k = 0; k < 4; ++k) {
            int e = base + k * 256;
            if (e < N_EDGES) {
                int r = fn_rows[e];
                int p = row_ptr[r] + fn_rank[e];
                csr_cv[p] = make_uint2((unsigned)fn_cols[e], __float_as_uint(fn_vals[e]));
            }
        }
#pragma unroll
        for (int k = 0; k < 4; ++k) {
            int e = base + k * 256;
            if (e < N_EDGES) {
                int r2 = nf_rows[e];
                if ((markbits[r2 >> 5] >> (r2 & 31)) & 1u) {
                    int p = row_ptr[M_NODES + r2] + nf_rank[e];
                    csr_cv[p] = make_uint2((unsigned)nf_cols[e], __float_as_uint(nf_vals[e]));
                }
            }
        }
        return;
    }

    // ---------------- gemm1 half ----------------
    const int tid  = threadIdx.x;
    const int lane = tid & 63;
    const int wv   = tid >> 6;
    const int l15  = lane & 15;
    const int g    = lane >> 4;
    const int row0 = blockIdx.x * 64;

    const int sr = tid >> 2;
    const int sc = tid & 3;
    const bool rowok = (row0 + sr) < N_NODES;
    const float* __restrict__ xrow = x + (size_t)(row0 + sr) * NFEAT;

    float cur[8], nxt[8];
    if (rowok) {
        float4 v0 = *(const float4*)&xrow[sc * 8 + 0];
        float4 v1 = *(const float4*)&xrow[sc * 8 + 4];
        cur[0] = v0.x; cur[1] = v0.y; cur[2] = v0.z; cur[3] = v0.w;
        cur[4] = v1.x; cur[5] = v1.y; cur[6] = v1.z; cur[7] = v1.w;
    } else {
#pragma unroll
        for (int j = 0; j < 8; ++j) cur[j] = 0.f;
    }

    f32x4 acc[4][4];
#pragma unroll
    for (int mf = 0; mf < 4; ++mf)
#pragma unroll
        for (int nf = 0; nf < 4; ++nf) acc[mf][nf] = (f32x4){0.f, 0.f, 0.f, 0.f};

    for (int t = 0; t < KTILES; ++t) {
        // ---- convert cur -> hi/lo, write LDS buf[t&1] (consumes prev loads) ----
        {
            bf16x8 hv, lv;
#pragma unroll
            for (int j = 0; j < 8; ++j) {
                unsigned short h = f2bf(cur[j]);
                hv[j] = (short)h;
                lv[j] = (short)f2bf(cur[j] - bf2f(h));
            }
            const int wo = sr * 40 + sc * 8;
            *(bf16x8*)&Ah[t & 1][wo] = hv;
            *(bf16x8*)&Al[t & 1][wo] = lv;
        }
        __syncthreads();

        // ---- issue next-tile loads AFTER the barrier: they fly under MFMA ----
        if (t < KTILES - 1) {
            const int k0 = (t + 1) * 32 + sc * 8;
            if (t + 1 < KTILES - 1) {
                if (rowok) {
                    float4 v0 = *(const float4*)&xrow[k0 + 0];
                    float4 v1 = *(const float4*)&xrow[k0 + 4];
                    nxt[0] = v0.x; nxt[1] = v0.y; nxt[2] = v0.z; nxt[3] = v0.w;
                    nxt[4] = v1.x; nxt[5] = v1.y; nxt[6] = v1.z; nxt[7] = v1.w;
                } else {
#pragma unroll
                    for (int j = 0; j < 8; ++j) nxt[j] = 0.f;
                }
            } else {                                 // tail tile: k 288..319
#pragma unroll
                for (int j = 0; j < 8; ++j) {
                    int k = k0 + j;
                    nxt[j] = (rowok && k < NFEAT) ? xrow[k] : 0.f;
                }
            }
        }

        // ---- compute ----
        const int b = t & 1;
        bf16x8 ah[4], al[4];
#pragma unroll
        for (int mf = 0; mf < 4; ++mf) {
            const int ao = (mf * 16 + l15) * 40 + g * 8;
            ah[mf] = *(const bf16x8*)&Ah[b][ao];
            al[mf] = *(const bf16x8*)&Al[b][ao];
        }
        bf16x8 bh[4], bl[4];
#pragma unroll
        for (int nf = 0; nf < 4; ++nf) {
            const size_t bo = (size_t)t * 8192 + (size_t)(wv * 64 + nf * 16 + l15) * 32 + g * 8;
            bh[nf] = *(const bf16x8*)&w1h[bo];
            bl[nf] = *(const bf16x8*)&w1l[bo];
        }
#pragma unroll
        for (int mf = 0; mf < 4; ++mf)
#pragma unroll
            for (int nf = 0; nf < 4; ++nf) {
                acc[mf][nf] = __builtin_amdgcn_mfma_f32_16x16x32_bf16(ah[mf], bh[nf], acc[mf][nf], 0, 0, 0);
                acc[mf][nf] = __builtin_amdgcn_mfma_f32_16x16x32_bf16(ah[mf], bl[nf], acc[mf][nf], 0, 0, 0);
                acc[mf][nf] = __builtin_amdgcn_mfma_f32_16x16x32_bf16(al[mf], bh[nf], acc[mf][nf], 0, 0, 0);
            }
#pragma unroll
        for (int j = 0; j < 8; ++j) cur[j] = nxt[j];
    }

    const int colb = wv * 64;
#pragma unroll
    for (int mf = 0; mf < 4; ++mf) {
        const int rg0 = row0 + mf * 16 + g * 4;
#pragma unroll
        for (int nf = 0; nf < 4; ++nf) {
            const int cg = colb + nf * 16 + l15;
#pragma unroll
            for (int j = 0; j < 4; ++j) {
                const int rg = rg0 + j;
                if (rg < N_NODES) xwb[(size_t)rg * NHID + cg] = f2bf(acc[mf][nf][j]);
            }
        }
    }
}

// ---------------------------------------------------------------------------
// FN spmm (bf16 gather): h[r] = relu(sum_j val_j * xw[col_j] + b1)
// one block (128 thr) per row. (round-7 version, at gather-service roofline)
// ---------------------------------------------------------------------------
__global__ __launch_bounds__(128) void spmm_fn_kernel(const int* __restrict__ row_ptr,
                                                      const uint2* __restrict__ csr_cv,
                                                      const unsigned* __restrict__ xwb,
                                                      const float* __restrict__ b1,
                                                      unsigned* __restrict__ hb) {
    const int r = blockIdx.x;
    const int t = threadIdx.x;          // 0..127 -> cols 2t, 2t+1
    const int s = row_ptr[r], e = row_ptr[r + 1];
    float a0 = 0.f, a1 = 0.f;
    int j = s;
    for (; j + 3 < e; j += 4) {
        uint2 cv0 = csr_cv[j],     cv1 = csr_cv[j + 1];
        uint2 cv2 = csr_cv[j + 2], cv3 = csr_cv[j + 3];
        float v0 = __uint_as_float(cv0.y), v1 = __uint_as_float(cv1.y);
        float v2 = __uint_as_float(cv2.y), v3 = __uint_as_float(cv3.y);
        unsigned x0 = xwb[(size_t)cv0.x * 128 + t];
        unsigned x1 = xwb[(size_t)cv1.x * 128 + t];
        unsigned x2 = xwb[(size_t)cv2.x * 128 + t];
        unsigned x3 = xwb[(size_t)cv3.x * 128 + t];
        a0 += v0 * bflo(x0); a1 += v0 * bfhi(x0);
        a0 += v1 * bflo(x1); a1 += v1 * bfhi(x1);
        a0 += v2 * bflo(x2); a1 += v2 * bfhi(x2);
        a0 += v3 * bflo(x3); a1 += v3 * bfhi(x3);
    }
    for (; j < e; ++j) {
        uint2 cv = csr_cv[j];
        float v = __uint_as_float(cv.y);
        unsigned xv = xwb[(size_t)cv.x * 128 + t];
        a0 += v * bflo(xv); a1 += v * bfhi(xv);
    }
    float2 bv = *(const float2*)&b1[t * 2];
    float o0 = fmaxf(a0 + bv.x, 0.f);
    float o1 = fmaxf(a1 + bv.y, 0.f);
    hb[(size_t)r * 128 + t] = ((unsigned)f2bf(o1) << 16) | (unsigned)f2bf(o0);
}

// ---------------------------------------------------------------------------
// GEMM2 via MFMA bf16x2 (hi+lo W2): hw = h(bf16) @ W2, fp32 out.
// ---------------------------------------------------------------------------
__global__ __launch_bounds__(256) void gemm2_mfma_kernel(const unsigned short* __restrict__ hb,
                                                         const unsigned short* __restrict__ w2h,
                                                         const unsigned short* __restrict__ w2l,
                                                         float* __restrict__ hw) {
    const int tid  = threadIdx.x;
    const int lane = tid & 63;
    const int wv   = tid >> 6;
    const int l15  = lane & 15;
    const int g    = lane >> 4;
    const int row0 = blockIdx.x * 64 + wv * 16;
    const int arow = row0 + l15;
    const bool rowok = arow < N_NODES;

    f32x4 acc[2];
    acc[0] = (f32x4){0.f, 0.f, 0.f, 0.f};
    acc[1] = (f32x4){0.f, 0.f, 0.f, 0.f};

#pragma unroll
    for (int t = 0; t < K2TILES; ++t) {
        bf16x8 a;
        if (rowok) a = *(const bf16x8*)&hb[(size_t)arow * NHID + t * 32 + g * 8];
        else {
#pragma unroll
            for (int j = 0; j < 8; ++j) a[j] = 0;
        }
#pragma unroll
        for (int nf = 0; nf < 2; ++nf) {
            const size_t bo = (size_t)t * 1024 + (size_t)(nf * 16 + l15) * 32 + g * 8;
            bf16x8 bh = *(const bf16x8*)&w2h[bo];
            bf16x8 bl = *(const bf16x8*)&w2l[bo];
            acc[nf] = __builtin_amdgcn_mfma_f32_16x16x32_bf16(a, bh, acc[nf], 0, 0, 0);
            acc[nf] = __builtin_amdgcn_mfma_f32_16x16x32_bf16(a, bl, acc[nf], 0, 0, 0);
        }
    }

#pragma unroll
    for (int nf = 0; nf < 2; ++nf) {
        const int col = nf * 16 + l15;
        if (col >= NCLASS) continue;
#pragma unroll
        for (int j = 0; j < 4; ++j) {
            const int row = row0 + g * 4 + j;
            if (row < N_NODES) hw[(size_t)row * NCLASS + col] = acc[nf][j];
        }
    }
}

// ---------------------------------------------------------------------------
// Fused NF-spmm + bias + softmax: one wave per idx entry.
// ---------------------------------------------------------------------------
__global__ __launch_bounds__(64) void spmm_nf_softmax_kernel(const int* __restrict__ idx,
                                                             const int* __restrict__ row_ptr,
                                                             const uint2* __restrict__ csr_cv,
                                                             const float* __restrict__ hw,
                                                             const float* __restrict__ b2,
                                                             float* __restrict__ out) {
    const int b    = blockIdx.x;
    const int lane = threadIdx.x;
    const int r = idx[b];
    const int s = row_ptr[M_NODES + r], e = row_ptr[M_NODES + r + 1];

    float acc[NCLASS];
#pragma unroll
    for (int k = 0; k < NCLASS; ++k) acc[k] = 0.f;

    for (int j = s + lane; j < e; j += 64) {
        uint2 cv = csr_cv[j];
        int   c = (int)cv.x;
        float v = __uint_as_float(cv.y);
        const float4* hp = (const float4*)&hw[(size_t)c * NCLASS];
        float4 h0 = hp[0], h1 = hp[1], h2 = hp[2], h3 = hp[3], h4 = hp[4];
        acc[0]  += v * h0.x; acc[1]  += v * h0.y; acc[2]  += v * h0.z; acc[3]  += v * h0.w;
        acc[4]  += v * h1.x; acc[5]  += v * h1.y; acc[6]  += v * h1.z; acc[7]  += v * h1.w;
        acc[8]  += v * h2.x; acc[9]  += v * h2.y; acc[10] += v * h2.z; acc[11] += v * h2.w;
        acc[12] += v * h3.x; acc[13] += v * h3.y; acc[14] += v * h3.z; acc[15] += v * h3.w;
        acc[16] += v * h4.x; acc[17] += v * h4.y; acc[18] += v * h4.z; acc[19] += v * h4.w;
    }

#pragma unroll
    for (int k = 0; k < NCLASS; ++k) {
#pragma unroll
        for (int off = 1; off < 64; off <<= 1) acc[k] += __shfl_xor(acc[k], off, 64);
    }

    if (lane == 0) {
        float v[NCLASS];
        float m = -1e30f;
#pragma unroll
        for (int k = 0; k < NCLASS; ++k) {
            v[k] = acc[k] + b2[k];
            m = fmaxf(m, v[k]);
        }
        float sum = 0.f;
#pragma unroll
        for (int k = 0; k < NCLASS; ++k) {
            v[k] = __expf(v[k] - m);
            sum += v[k];
        }
        float inv = 1.f / sum;
#pragma unroll
        for (int k = 0; k < NCLASS; ++k) out[(size_t)b * NCLASS + k] = v[k] * inv;
    }
}

// ---------------------------------------------------------------------------
extern "C" void kernel_launch(void* const* d_in, const int* in_sizes, int n_in,
                              void* d_out, int out_size, void* d_ws, size_t ws_size,
                              hipStream_t stream) {
    const float* x       = (const float*)d_in[0];
    const int*   fn_rows = (const int*)  d_in[1];
    const int*   fn_cols = (const int*)  d_in[2];
    const float* fn_vals = (const float*)d_in[3];
    const int*   nf_rows = (const int*)  d_in[4];
    const int*   nf_cols = (const int*)  d_in[5];
    const float* nf_vals = (const float*)d_in[6];
    const int*   idx     = (const int*)  d_in[7];
    const float* W1      = (const float*)d_in[8];
    const float* b1      = (const float*)d_in[9];
    const float* W2      = (const float*)d_in[10];
    const float* b2      = (const float*)d_in[11];
    float* out = (float*)d_out;

    size_t off = 0;
    auto alloc = [&](size_t bytes) {
        void* p = (char*)d_ws + off;
        off += (bytes + 255) & ~(size_t)255;
        return p;
    };
    unsigned short* xwb = (unsigned short*)alloc((size_t)N_NODES * NHID * 2);  // 25.6 MB
    unsigned*       hb  = (unsigned*)      alloc((size_t)M_NODES * NHID * 2);  // 25.6 MB
    float* hw       = (float*)alloc((size_t)M_NODES * NCLASS * 4);             // 4 MB
    // counts and markbits contiguous -> single memset
    int*      counts   = (int*)     alloc((size_t)NTOT * 4);
    unsigned* markbits = (unsigned*)alloc((size_t)MARKW * 4);
    int*   row_ptr  = (int*)  alloc((size_t)(NTOT + 1) * 4);
    uint2* csr_cv   = (uint2*)alloc((size_t)2 * N_EDGES * 8);
    unsigned short* fn_rank = (unsigned short*)alloc((size_t)N_EDGES * 2);
    unsigned short* nf_rank = (unsigned short*)alloc((size_t)N_EDGES * 2);
    int*   chunk_incl = (int*)alloc((size_t)NTOT * 4);
    int*   chunk_sums = (int*)alloc(512 * 4);
    unsigned short* w1h = (unsigned short*)alloc((size_t)KTILES * 256 * 32 * 2);
    unsigned short* w1l = (unsigned short*)alloc((size_t)KTILES * 256 * 32 * 2);
    unsigned short* w2h = (unsigned short*)alloc((size_t)K2TILES * 32 * 32 * 2);  // 16 KB
    unsigned short* w2l = (unsigned short*)alloc((size_t)K2TILES * 32 * 32 * 2);
    (void)ws_size; (void)n_in; (void)in_sizes; (void)out_size;

    const int NCHUNKS_ALL = (NTOT + 255) / 256;     // 391

    // single memset covering counts + markbits (contiguous in ws)
    size_t zlen = (size_t)((char*)markbits - (char*)counts) + (size_t)MARKW * 4;
    hipMemsetAsync(counts, 0, zlen, stream);

    // fused prep: W1 hi/lo + mark bitmask + W2 hi/lo
    prep_kernel<<<372, 256, 0, stream>>>(W1, w1h, w1l, idx, markbits, W2, w2h, w2l);

    // combined CSR hist (FN + marked-NF), rank captured
    hist_both_kernel<<<EB4_BLOCKS, 256, 0, stream>>>(fn_rows, nf_rows, markbits, counts, fn_rank, nf_rank);
    scan_chunk_kernel<<<NCHUNKS_ALL, 256, 0, stream>>>(counts, chunk_incl, chunk_sums, NTOT);
    scan_finish_kernel<<<NCHUNKS_ALL, 256, 0, stream>>>(counts, chunk_incl, chunk_sums,
                                                        row_ptr, NTOT, NCHUNKS_ALL);

    // FUSED (contiguous): gemm1 (MFMA bf16x3, post-barrier prefetch) + scatter
    gemm1_scatter_kernel<<<GEMM1_BLOCKS + EB4_BLOCKS, 256, 0, stream>>>(
        x, w1h, w1l, xwb,
        fn_rows, fn_cols, fn_vals, nf_rows, nf_cols, nf_vals,
        markbits, row_ptr, fn_rank, nf_rank, csr_cv);

    // FN spmm + bias + relu (bf16 in, bf16 out)
    spmm_fn_kernel<<<M_NODES, 128, 0, stream>>>(row_ptr, csr_cv, (const unsigned*)xwb, b1, hb);

    // GEMM2 via MFMA (bf16 h, hi/lo W2)
    gemm2_mfma_kernel<<<(N_NODES + 63) / 64, 256, 0, stream>>>((const unsigned short*)hb, w2h, w2l, hw);

    // fused NF spmm + bias + softmax -> out
    spmm_nf_softmax_kernel<<<N_IDX, 64, 0, stream>>>(idx, row_ptr, csr_cv, hw, b2, out);
}

// Round 16
// 188.937 us; speedup vs baseline: 1.0214x; 1.0214x over previous
//
#include <hip/hip_runtime.h>

#define N_NODES 50000
#define M_NODES 50000
#define N_EDGES 800000
#define NFEAT   300
#define NHID    256
#define NCLASS  20
#define N_IDX   5000
#define KTILES  10          // ceil(300/32) for gemm1
#define K2TILES 8           // 256/32 for gemm2
#define NTOT    (M_NODES + N_NODES)
#define MARKW   ((N_NODES + 31) / 32)
#define GEMM1_BLOCKS ((N_NODES + 63) / 64)     // 782
#define EB4_BLOCKS   ((N_EDGES + 1023) / 1024) // 782 (scatter: 4 edges/thread)
#define EB8_BLOCKS   ((N_EDGES + 2047) / 2048) // 391 (hist: 8 edges/thread)

typedef __attribute__((ext_vector_type(8))) short bf16x8;
typedef __attribute__((ext_vector_type(4))) float f32x4;

__device__ inline unsigned short f2bf(float f) {
    unsigned u = __float_as_uint(f);
    u += 0x7fff + ((u >> 16) & 1);          // round-to-nearest-even
    return (unsigned short)(u >> 16);
}
__device__ inline float bf2f(unsigned short h) { return __uint_as_float((unsigned)h << 16); }
__device__ inline float bflo(unsigned v) { return __uint_as_float(v << 16); }
__device__ inline float bfhi(unsigned v) { return __uint_as_float(v & 0xffff0000u); }

// ---------------------------------------------------------------------------
// Fused prep: blocks [0,320) W1 -> k-tiled hi/lo bf16;
//             blocks [320,340) mark bitmask;
//             blocks [340,372) W2 -> k-tiled hi/lo bf16 (cols padded to 32).
// ---------------------------------------------------------------------------
__global__ __launch_bounds__(256) void prep_kernel(const float* __restrict__ W1,
                                                   unsigned short* __restrict__ w1h,
                                                   unsigned short* __restrict__ w1l,
                                                   const int* __restrict__ idx,
                                                   unsigned* __restrict__ markbits,
                                                   const float* __restrict__ W2,
                                                   unsigned short* __restrict__ w2h,
                                                   unsigned short* __restrict__ w2l) {
    if (blockIdx.x < 320) {
        int id = blockIdx.x * 256 + threadIdx.x;        // 320*256 total
        int col = id & 255;
        int k   = id >> 8;                              // 0..319
        float v = (k < NFEAT) ? W1[(size_t)k * NHID + col] : 0.f;
        unsigned short hi = f2bf(v);
        unsigned short lo = f2bf(v - bf2f(hi));
        size_t off = (size_t)(k >> 5) * (256 * 32) + (size_t)col * 32 + (k & 31);
        w1h[off] = hi;
        w1l[off] = lo;
    } else if (blockIdx.x < 340) {
        int i = (blockIdx.x - 320) * 256 + threadIdx.x;
        if (i < N_IDX) {
            int r = idx[i];
            atomicOr(&markbits[r >> 5], 1u << (r & 31));
        }
    } else {
        int id = (blockIdx.x - 340) * 256 + threadIdx.x;  // 8192 = 256k x 32col
        int col = id & 31;
        int k   = id >> 5;                                // 0..255
        float v = (col < NCLASS) ? W2[(size_t)k * NCLASS + col] : 0.f;
        unsigned short hi = f2bf(v);
        unsigned short lo = f2bf(v - bf2f(hi));
        size_t off = (size_t)(k >> 5) * (32 * 32) + (size_t)col * 32 + (k & 31);
        w2h[off] = hi;
        w2l[off] = lo;
    }
}

// ---------------------------------------------------------------------------
// Combined histogram + rank capture, 8 edges/thread (2x MLP on atomic chains)
// counts[0..M) = FN rows; counts[M..M+N) = NF rows (marked via L1-hot bitmask)
// ---------------------------------------------------------------------------
__global__ __launch_bounds__(256) void hist_both_kernel(const int* __restrict__ fn_rows,
                                                        const int* __restrict__ nf_rows,
                                                        const unsigned* __restrict__ markbits,
                                                        int* __restrict__ counts,
                                                        unsigned short* __restrict__ fn_rank,
                                                        unsigned short* __restrict__ nf_rank) {
    const int base = blockIdx.x * 2048 + threadIdx.x;
    int r[8], r2[8], m2[8];
#pragma unroll
    for (int k = 0; k < 8; ++k) {
        int e = base + k * 256;
        r[k]  = (e < N_EDGES) ? fn_rows[e] : -1;
        r2[k] = (e < N_EDGES) ? nf_rows[e] : -1;
    }
#pragma unroll
    for (int k = 0; k < 8; ++k)
        m2[k] = (r2[k] >= 0) ? (int)((markbits[r2[k] >> 5] >> (r2[k] & 31)) & 1u) : 0;
#pragma unroll
    for (int k = 0; k < 8; ++k) {
        if (r[k] >= 0) {
            int p = atomicAdd(&counts[r[k]], 1);
            fn_rank[base + k * 256] = (unsigned short)p;
        }
    }
#pragma unroll
    for (int k = 0; k < 8; ++k) {
        if (m2[k]) {
            int p = atomicAdd(&counts[M_NODES + r2[k]], 1);
            nf_rank[base + k * 256] = (unsigned short)p;
        }
    }
}

// ---------------------------------------------------------------------------
// Scan pass 1: per-chunk inclusive scan + chunk totals
// ---------------------------------------------------------------------------
__global__ __launch_bounds__(256) void scan_chunk_kernel(const int* __restrict__ counts,
                                                         int* __restrict__ chunk_incl,
                                                         int* __restrict__ chunk_sums, int n) {
    __shared__ int lds[256];
    int i = blockIdx.x * 256 + threadIdx.x;
    int v = (i < n) ? counts[i] : 0;
    lds[threadIdx.x] = v;
    __syncthreads();
    for (int off = 1; off < 256; off <<= 1) {
        int t = (threadIdx.x >= off) ? lds[threadIdx.x - off] : 0;
        __syncthreads();
        lds[threadIdx.x] += t;
        __syncthreads();
    }
    if (i < n) chunk_incl[i] = lds[threadIdx.x];
    if (threadIdx.x == 255) chunk_sums[blockIdx.x] = lds[255];
}

// ---------------------------------------------------------------------------
// Scan pass 2 (merged): per-block prefix over chunk_sums + apply.
// ---------------------------------------------------------------------------
__global__ __launch_bounds__(256) void scan_finish_kernel(const int* __restrict__ counts,
                                                          const int* __restrict__ chunk_incl,
                                                          const int* __restrict__ chunk_sums,
                                                          int* __restrict__ row_ptr,
                                                          int n, int nchunks) {
    __shared__ int lds[256];
    const int b = blockIdx.x;
    int partial = 0;
    for (int i = threadIdx.x; i < b; i += 256) partial += chunk_sums[i];
    lds[threadIdx.x] = partial;
    __syncthreads();
    for (int off = 128; off > 0; off >>= 1) {
        if (threadIdx.x < off) lds[threadIdx.x] += lds[threadIdx.x + off];
        __syncthreads();
    }
    const int coff = lds[0];
    int i = b * 256 + threadIdx.x;
    if (i < n) row_ptr[i] = chunk_incl[i] - counts[i] + coff;
    if (b == nchunks - 1 && threadIdx.x == 0) row_ptr[n] = coff + chunk_sums[b];
}

// ---------------------------------------------------------------------------
// FUSED gemm1 + scatter, CONTIGUOUS ranges (round-14 K-loop order: prefetch
// issued BEFORE the LDS-write+barrier — the measured-best schedule).
// ---------------------------------------------------------------------------
__global__ __launch_bounds__(256) void gemm1_scatter_kernel(
        const float* __restrict__ x,
        const unsigned short* __restrict__ w1h,
        const unsigned short* __restrict__ w1l,
        unsigned short* __restrict__ xwb,
        const int* __restrict__ fn_rows, const int* __restrict__ fn_cols,
        const float* __restrict__ fn_vals,
        const int* __restrict__ nf_rows, const int* __restrict__ nf_cols,
        const float* __restrict__ nf_vals,
        const unsigned* __restrict__ markbits,
        const int* __restrict__ row_ptr,
        const unsigned short* __restrict__ fn_rank,
        const unsigned short* __restrict__ nf_rank,
        uint2* __restrict__ csr_cv) {
    __shared__ unsigned short Ah[2][64 * 40];   // 40 = 32 + 8 pad (80B rows)
    __shared__ unsigned short Al[2][64 * 40];

    if (blockIdx.x >= GEMM1_BLOCKS) {
        // ---------------- scatter half ----------------
        const int base = (blockIdx.x - GEMM1_BLOCKS) * 1024 + threadIdx.x;
#pragma unroll
        for (int k = 0; k < 4; ++k) {
            int e = base + k * 256;
            if (e < N_EDGES) {
                int r = fn_rows[e];
                int p = row_ptr[r] + fn_rank[e];
                csr_cv[p] = make_uint2((unsigned)fn_cols[e], __float_as_uint(fn_vals[e]));
            }
        }
#pragma unroll
        for (int k = 0; k < 4; ++k) {
            int e = base + k * 256;
            if (e < N_EDGES) {
                int r2 = nf_rows[e];
                if ((markbits[r2 >> 5] >> (r2 & 31)) & 1u) {
                    int p = row_ptr[M_NODES + r2] + nf_rank[e];
                    csr_cv[p] = make_uint2((unsigned)nf_cols[e], __float_as_uint(nf_vals[e]));
                }
            }
        }
        return;
    }

    // ---------------- gemm1 half ----------------
    const int tid  = threadIdx.x;
    const int lane = tid & 63;
    const int wv   = tid >> 6;
    const int l15  = lane & 15;
    const int g    = lane >> 4;
    const int row0 = blockIdx.x * 64;

    const int sr = tid >> 2;
    const int sc = tid & 3;
    const bool rowok = (row0 + sr) < N_NODES;
    const float* __restrict__ xrow = x + (size_t)(row0 + sr) * NFEAT;

    float cur[8], nxt[8];
    if (rowok) {
        float4 v0 = *(const float4*)&xrow[sc * 8 + 0];
        float4 v1 = *(const float4*)&xrow[sc * 8 + 4];
        cur[0] = v0.x; cur[1] = v0.y; cur[2] = v0.z; cur[3] = v0.w;
        cur[4] = v1.x; cur[5] = v1.y; cur[6] = v1.z; cur[7] = v1.w;
    } else {
#pragma unroll
        for (int j = 0; j < 8; ++j) cur[j] = 0.f;
    }

    f32x4 acc[4][4];
#pragma unroll
    for (int mf = 0; mf < 4; ++mf)
#pragma unroll
        for (int nf = 0; nf < 4; ++nf) acc[mf][nf] = (f32x4){0.f, 0.f, 0.f, 0.f};

    for (int t = 0; t < KTILES; ++t) {
        if (t < KTILES - 1) {
            const int k0 = (t + 1) * 32 + sc * 8;
            if (t + 1 < KTILES - 1) {
                if (rowok) {
                    float4 v0 = *(const float4*)&xrow[k0 + 0];
                    float4 v1 = *(const float4*)&xrow[k0 + 4];
                    nxt[0] = v0.x; nxt[1] = v0.y; nxt[2] = v0.z; nxt[3] = v0.w;
                    nxt[4] = v1.x; nxt[5] = v1.y; nxt[6] = v1.z; nxt[7] = v1.w;
                } else {
#pragma unroll
                    for (int j = 0; j < 8; ++j) nxt[j] = 0.f;
                }
            } else {
#pragma unroll
                for (int j = 0; j < 8; ++j) {
                    int k = k0 + j;
                    nxt[j] = (rowok && k < NFEAT) ? xrow[k] : 0.f;
                }
            }
        }

        {
            bf16x8 hv, lv;
#pragma unroll
            for (int j = 0; j < 8; ++j) {
                unsigned short h = f2bf(cur[j]);
                hv[j] = (short)h;
                lv[j] = (short)f2bf(cur[j] - bf2f(h));
            }
            const int wo = sr * 40 + sc * 8;
            *(bf16x8*)&Ah[t & 1][wo] = hv;
            *(bf16x8*)&Al[t & 1][wo] = lv;
        }
        __syncthreads();

        const int b = t & 1;
        bf16x8 ah[4], al[4];
#pragma unroll
        for (int mf = 0; mf < 4; ++mf) {
            const int ao = (mf * 16 + l15) * 40 + g * 8;
            ah[mf] = *(const bf16x8*)&Ah[b][ao];
            al[mf] = *(const bf16x8*)&Al[b][ao];
        }
        bf16x8 bh[4], bl[4];
#pragma unroll
        for (int nf = 0; nf < 4; ++nf) {
            const size_t bo = (size_t)t * 8192 + (size_t)(wv * 64 + nf * 16 + l15) * 32 + g * 8;
            bh[nf] = *(const bf16x8*)&w1h[bo];
            bl[nf] = *(const bf16x8*)&w1l[bo];
        }
#pragma unroll
        for (int mf = 0; mf < 4; ++mf)
#pragma unroll
            for (int nf = 0; nf < 4; ++nf) {
                acc[mf][nf] = __builtin_amdgcn_mfma_f32_16x16x32_bf16(ah[mf], bh[nf], acc[mf][nf], 0, 0, 0);
                acc[mf][nf] = __builtin_amdgcn_mfma_f32_16x16x32_bf16(ah[mf], bl[nf], acc[mf][nf], 0, 0, 0);
                acc[mf][nf] = __builtin_amdgcn_mfma_f32_16x16x32_bf16(al[mf], bh[nf], acc[mf][nf], 0, 0, 0);
            }
#pragma unroll
        for (int j = 0; j < 8; ++j) cur[j] = nxt[j];
    }

    const int colb = wv * 64;
#pragma unroll
    for (int mf = 0; mf < 4; ++mf) {
        const int rg0 = row0 + mf * 16 + g * 4;
#pragma unroll
        for (int nf = 0; nf < 4; ++nf) {
            const int cg = colb + nf * 16 + l15;
#pragma unroll
            for (int j = 0; j < 4; ++j) {
                const int rg = rg0 + j;
                if (rg < N_NODES) xwb[(size_t)rg * NHID + cg] = f2bf(acc[mf][nf][j]);
            }
        }
    }
}

// ---------------------------------------------------------------------------
// FN spmm (bf16 gather): h[r] = relu(sum_j val_j * xw[col_j] + b1)
// one block (128 thr) per row. (round-7 version, at gather-service roofline)
// ---------------------------------------------------------------------------
__global__ __launch_bounds__(128) void spmm_fn_kernel(const int* __restrict__ row_ptr,
                                                      const uint2* __restrict__ csr_cv,
                                                      const unsigned* __restrict__ xwb,
                                                      const float* __restrict__ b1,
                                                      unsigned* __restrict__ hb) {
    const int r = blockIdx.x;
    const int t = threadIdx.x;          // 0..127 -> cols 2t, 2t+1
    const int s = row_ptr[r], e = row_ptr[r + 1];
    float a0 = 0.f, a1 = 0.f;
    int j = s;
    for (; j + 3 < e; j += 4) {
        uint2 cv0 = csr_cv[j],     cv1 = csr_cv[j + 1];
        uint2 cv2 = csr_cv[j + 2], cv3 = csr_cv[j + 3];
        float v0 = __uint_as_float(cv0.y), v1 = __uint_as_float(cv1.y);
        float v2 = __uint_as_float(cv2.y), v3 = __uint_as_float(cv3.y);
        unsigned x0 = xwb[(size_t)cv0.x * 128 + t];
        unsigned x1 = xwb[(size_t)cv1.x * 128 + t];
        unsigned x2 = xwb[(size_t)cv2.x * 128 + t];
        unsigned x3 = xwb[(size_t)cv3.x * 128 + t];
        a0 += v0 * bflo(x0); a1 += v0 * bfhi(x0);
        a0 += v1 * bflo(x1); a1 += v1 * bfhi(x1);
        a0 += v2 * bflo(x2); a1 += v2 * bfhi(x2);
        a0 += v3 * bflo(x3); a1 += v3 * bfhi(x3);
    }
    for (; j < e; ++j) {
        uint2 cv = csr_cv[j];
        float v = __uint_as_float(cv.y);
        unsigned xv = xwb[(size_t)cv.x * 128 + t];
        a0 += v * bflo(xv); a1 += v * bfhi(xv);
    }
    float2 bv = *(const float2*)&b1[t * 2];
    float o0 = fmaxf(a0 + bv.x, 0.f);
    float o1 = fmaxf(a1 + bv.y, 0.f);
    hb[(size_t)r * 128 + t] = ((unsigned)f2bf(o1) << 16) | (unsigned)f2bf(o0);
}

// ---------------------------------------------------------------------------
// GEMM2 via MFMA bf16x2 (hi+lo W2): hw = h(bf16) @ W2, fp32 out.
// ---------------------------------------------------------------------------
__global__ __launch_bounds__(256) void gemm2_mfma_kernel(const unsigned short* __restrict__ hb,
                                                         const unsigned short* __restrict__ w2h,
                                                         const unsigned short* __restrict__ w2l,
                                                         float* __restrict__ hw) {
    const int tid  = threadIdx.x;
    const int lane = tid & 63;
    const int wv   = tid >> 6;
    const int l15  = lane & 15;
    const int g    = lane >> 4;
    const int row0 = blockIdx.x * 64 + wv * 16;
    const int arow = row0 + l15;
    const bool rowok = arow < N_NODES;

    f32x4 acc[2];
    acc[0] = (f32x4){0.f, 0.f, 0.f, 0.f};
    acc[1] = (f32x4){0.f, 0.f, 0.f, 0.f};

#pragma unroll
    for (int t = 0; t < K2TILES; ++t) {
        bf16x8 a;
        if (rowok) a = *(const bf16x8*)&hb[(size_t)arow * NHID + t * 32 + g * 8];
        else {
#pragma unroll
            for (int j = 0; j < 8; ++j) a[j] = 0;
        }
#pragma unroll
        for (int nf = 0; nf < 2; ++nf) {
            const size_t bo = (size_t)t * 1024 + (size_t)(nf * 16 + l15) * 32 + g * 8;
            bf16x8 bh = *(const bf16x8*)&w2h[bo];
            bf16x8 bl = *(const bf16x8*)&w2l[bo];
            acc[nf] = __builtin_amdgcn_mfma_f32_16x16x32_bf16(a, bh, acc[nf], 0, 0, 0);
            acc[nf] = __builtin_amdgcn_mfma_f32_16x16x32_bf16(a, bl, acc[nf], 0, 0, 0);
        }
    }

#pragma unroll
    for (int nf = 0; nf < 2; ++nf) {
        const int col = nf * 16 + l15;
        if (col >= NCLASS) continue;
#pragma unroll
        for (int j = 0; j < 4; ++j) {
            const int row = row0 + g * 4 + j;
            if (row < N_NODES) hw[(size_t)row * NCLASS + col] = acc[nf][j];
        }
    }
}

// ---------------------------------------------------------------------------
// Fused NF-spmm + bias + softmax: one wave per idx entry.
// ---------------------------------------------------------------------------
__global__ __launch_bounds__(64) void spmm_nf_softmax_kernel(const int* __restrict__ idx,
                                                             const int* __restrict__ row_ptr,
                                                             const uint2* __restrict__ csr_cv,
                                                             const float* __restrict__ hw,
                                                             const float* __restrict__ b2,
                                                             float* __restrict__ out) {
    const int b    = blockIdx.x;
    const int lane = threadIdx.x;
    const int r = idx[b];
    const int s = row_ptr[M_NODES + r], e = row_ptr[M_NODES + r + 1];

    float acc[NCLASS];
#pragma unroll
    for (int k = 0; k < NCLASS; ++k) acc[k] = 0.f;

    for (int j = s + lane; j < e; j += 64) {
        uint2 cv = csr_cv[j];
        int   c = (int)cv.x;
        float v = __uint_as_float(cv.y);
        const float4* hp = (const float4*)&hw[(size_t)c * NCLASS];
        float4 h0 = hp[0], h1 = hp[1], h2 = hp[2], h3 = hp[3], h4 = hp[4];
        acc[0]  += v * h0.x; acc[1]  += v * h0.y; acc[2]  += v * h0.z; acc[3]  += v * h0.w;
        acc[4]  += v * h1.x; acc[5]  += v * h1.y; acc[6]  += v * h1.z; acc[7]  += v * h1.w;
        acc[8]  += v * h2.x; acc[9]  += v * h2.y; acc[10] += v * h2.z; acc[11] += v * h2.w;
        acc[12] += v * h3.x; acc[13] += v * h3.y; acc[14] += v * h3.z; acc[15] += v * h3.w;
        acc[16] += v * h4.x; acc[17] += v * h4.y; acc[18] += v * h4.z; acc[19] += v * h4.w;
    }

#pragma unroll
    for (int k = 0; k < NCLASS; ++k) {
#pragma unroll
        for (int off = 1; off < 64; off <<= 1) acc[k] += __shfl_xor(acc[k], off, 64);
    }

    if (lane == 0) {
        float v[NCLASS];
        float m = -1e30f;
#pragma unroll
        for (int k = 0; k < NCLASS; ++k) {
            v[k] = acc[k] + b2[k];
            m = fmaxf(m, v[k]);
        }
        float sum = 0.f;
#pragma unroll
        for (int k = 0; k < NCLASS; ++k) {
            v[k] = __expf(v[k] - m);
            sum += v[k];
        }
        float inv = 1.f / sum;
#pragma unroll
        for (int k = 0; k < NCLASS; ++k) out[(size_t)b * NCLASS + k] = v[k] * inv;
    }
}

// ---------------------------------------------------------------------------
extern "C" void kernel_launch(void* const* d_in, const int* in_sizes, int n_in,
                              void* d_out, int out_size, void* d_ws, size_t ws_size,
                              hipStream_t stream) {
    const float* x       = (const float*)d_in[0];
    const int*   fn_rows = (const int*)  d_in[1];
    const int*   fn_cols = (const int*)  d_in[2];
    const float* fn_vals = (const float*)d_in[3];
    const int*   nf_rows = (const int*)  d_in[4];
    const int*   nf_cols = (const int*)  d_in[5];
    const float* nf_vals = (const float*)d_in[6];
    const int*   idx     = (const int*)  d_in[7];
    const float* W1      = (const float*)d_in[8];
    const float* b1      = (const float*)d_in[9];
    const float* W2      = (const float*)d_in[10];
    const float* b2      = (const float*)d_in[11];
    float* out = (float*)d_out;

    size_t off = 0;
    auto alloc = [&](size_t bytes) {
        void* p = (char*)d_ws + off;
        off += (bytes + 255) & ~(size_t)255;
        return p;
    };
    unsigned short* xwb = (unsigned short*)alloc((size_t)N_NODES * NHID * 2);  // 25.6 MB
    unsigned*       hb  = (unsigned*)      alloc((size_t)M_NODES * NHID * 2);  // 25.6 MB
    float* hw       = (float*)alloc((size_t)M_NODES * NCLASS * 4);             // 4 MB
    // counts and markbits contiguous -> single memset
    int*      counts   = (int*)     alloc((size_t)NTOT * 4);
    unsigned* markbits = (unsigned*)alloc((size_t)MARKW * 4);
    int*   row_ptr  = (int*)  alloc((size_t)(NTOT + 1) * 4);
    uint2* csr_cv   = (uint2*)alloc((size_t)2 * N_EDGES * 8);
    unsigned short* fn_rank = (unsigned short*)alloc((size_t)N_EDGES * 2);
    unsigned short* nf_rank = (unsigned short*)alloc((size_t)N_EDGES * 2);
    int*   chunk_incl = (int*)alloc((size_t)NTOT * 4);
    int*   chunk_sums = (int*)alloc(512 * 4);
    unsigned short* w1h = (unsigned short*)alloc((size_t)KTILES * 256 * 32 * 2);
    unsigned short* w1l = (unsigned short*)alloc((size_t)KTILES * 256 * 32 * 2);
    unsigned short* w2h = (unsigned short*)alloc((size_t)K2TILES * 32 * 32 * 2);  // 16 KB
    unsigned short* w2l = (unsigned short*)alloc((size_t)K2TILES * 32 * 32 * 2);
    (void)ws_size; (void)n_in; (void)in_sizes; (void)out_size;

    const int NCHUNKS_ALL = (NTOT + 255) / 256;     // 391

    // single memset covering counts + markbits (contiguous in ws)
    size_t zlen = (size_t)((char*)markbits - (char*)counts) + (size_t)MARKW * 4;
    hipMemsetAsync(counts, 0, zlen, stream);

    // fused prep: W1 hi/lo + mark bitmask + W2 hi/lo
    prep_kernel<<<372, 256, 0, stream>>>(W1, w1h, w1l, idx, markbits, W2, w2h, w2l);

    // combined CSR hist (FN + marked-NF), rank captured, 8 edges/thread
    hist_both_kernel<<<EB8_BLOCKS, 256, 0, stream>>>(fn_rows, nf_rows, markbits, counts, fn_rank, nf_rank);
    scan_chunk_kernel<<<NCHUNKS_ALL, 256, 0, stream>>>(counts, chunk_incl, chunk_sums, NTOT);
    scan_finish_kernel<<<NCHUNKS_ALL, 256, 0, stream>>>(counts, chunk_incl, chunk_sums,
                                                        row_ptr, NTOT, NCHUNKS_ALL);

    // FUSED (contiguous): gemm1 (MFMA bf16x3, round-14 schedule) + scatter
    gemm1_scatter_kernel<<<GEMM1_BLOCKS + EB4_BLOCKS, 256, 0, stream>>>(
        x, w1h, w1l, xwb,
        fn_rows, fn_cols, fn_vals, nf_rows, nf_cols, nf_vals,
        markbits, row_ptr, fn_rank, nf_rank, csr_cv);

    // FN spmm + bias + relu (bf16 in, bf16 out)
    spmm_fn_kernel<<<M_NODES, 128, 0, stream>>>(row_ptr, csr_cv, (const unsigned*)xwb, b1, hb);

    // GEMM2 via MFMA (bf16 h, hi/lo W2)
    gemm2_mfma_kernel<<<(N_NODES + 63) / 64, 256, 0, stream>>>((const unsigned short*)hb, w2h, w2l, hw);

    // fused NF spmm + bias + softmax -> out
    spmm_nf_softmax_kernel<<<N_IDX, 64, 0, stream>>>(idx, row_ptr, csr_cv, hw, b2, out);
}